// Round 7
// baseline (293.384 us; speedup 1.0000x reference)
//
#include <hip/hip_runtime.h>
#include <hip/hip_bf16.h>

typedef __hip_bfloat16 bf16;
typedef __attribute__((ext_vector_type(8))) short          bf16x8;
typedef __attribute__((ext_vector_type(4))) float          f32x4;
typedef __attribute__((ext_vector_type(4))) int            i32x4;
typedef __attribute__((ext_vector_type(8))) int            i32x8;

#define C_DIM 512
#define NSP   4096

__device__ __forceinline__ unsigned char f2fp8(float x) {
  return (unsigned char)(__builtin_amdgcn_cvt_pk_fp8_f32(x, x, 0, false) & 0xFF);
}

// ---------------- f32 -> bf16 convert (512x512 weight) ----------------
__global__ __launch_bounds__(256) void cvt_bf16(const float* __restrict__ s,
                                                bf16* __restrict__ d) {
  const int i = (blockIdx.x * 256 + threadIdx.x) * 4;
  const float4 v = *reinterpret_cast<const float4*>(s + i);
  d[i + 0] = __float2bfloat16(v.x);
  d[i + 1] = __float2bfloat16(v.y);
  d[i + 2] = __float2bfloat16(v.z);
  d[i + 3] = __float2bfloat16(v.w);
}

// ---------------- f32 512x512 -> bf16 transposed ----------------
__global__ __launch_bounds__(256) void cvt_bf16_T(const float* __restrict__ s,
                                                  bf16* __restrict__ d) {
  __shared__ float tile[32][33];
  const int c0 = blockIdx.x * 32, r0 = blockIdx.y * 32;
  const int tx = threadIdx.x & 31, ty = threadIdx.x >> 5;
  #pragma unroll
  for (int i = 0; i < 32; i += 8)
    tile[ty + i][tx] = s[(size_t)(r0 + ty + i) * 512 + c0 + tx];
  __syncthreads();
  #pragma unroll
  for (int i = 0; i < 32; i += 8)
    d[(size_t)(c0 + ty + i) * 512 + r0 + tx] = __float2bfloat16(tile[tx][ty + i]);
}

// ---------------- composed biases: out[w*512+o] = b_w[o] + sum_c W_w[o,c] bg[c] ----------------
__global__ __launch_bounds__(256)
void bias_compose(const float* __restrict__ w_th, const float* __restrict__ b_th,
                  const float* __restrict__ w_ph, const float* __restrict__ b_ph,
                  const float* __restrict__ w_g,  const float* __restrict__ b_g,
                  float* __restrict__ out)
{
  const int idx = blockIdx.x * 256 + threadIdx.x;   // grid 6 -> 1536
  const int w = idx >> 9, o = idx & 511;
  const float* W  = (w == 0) ? w_th : (w == 1) ? w_ph : w_g;
  const float* bb = (w == 0) ? b_th : (w == 1) ? b_ph : b_g;
  const float4* row = reinterpret_cast<const float4*>(W + (size_t)o * 512);
  const float4* bg4 = reinterpret_cast<const float4*>(b_g);
  float s = bb[o];
  #pragma unroll 4
  for (int i = 0; i < 128; ++i) {
    const float4 a = row[i], c = bg4[i];
    s += a.x * c.x + a.y * c.y + a.z * c.z + a.w * c.w;
  }
  out[idx] = s;
}

// ---------------- x (B,C,N) f32 -> XT (B*N, C) bf16 ----------------
__global__ __launch_bounds__(256) void transpose_x(const float* __restrict__ x,
                                                   bf16* __restrict__ xt) {
  __shared__ float tile[32][33];
  const int n0 = blockIdx.x * 32, c0 = blockIdx.y * 32, b = blockIdx.z;
  const int tx = threadIdx.x & 31, ty = threadIdx.x >> 5;
  const float* src = x + ((size_t)b * C_DIM + c0) * NSP + n0;
  #pragma unroll
  for (int i = 0; i < 32; i += 8)
    tile[ty + i][tx] = src[(size_t)(ty + i) * NSP + tx];
  __syncthreads();
  bf16* dst = xt + ((size_t)b * NSP + n0) * C_DIM + c0;
  #pragma unroll
  for (int i = 0; i < 32; i += 8)
    dst[(size_t)(ty + i) * C_DIM + tx] = __float2bfloat16(tile[tx][ty + i]);
}

// ---------------- Linv: Lp[16384][64] partial sums -> 1/rowsum ----------------
__global__ __launch_bounds__(256) void lreduce(const float* __restrict__ Lp,
                                               float* __restrict__ Linv) {
  const int r = blockIdx.x * 256 + threadIdx.x;
  const float4* p = reinterpret_cast<const float4*>(Lp + (size_t)r * 64);
  float s = 0.0f;
  #pragma unroll
  for (int i = 0; i < 16; ++i) { const float4 v = p[i]; s += (v.x + v.y) + (v.z + v.w); }
  Linv[r] = 1.0f / s;
}

// ======================= bf16 NT GEMM =======================
// 128x128 tile, BK=32, 256 thr, 16x16x32 bf16 MFMA.
// T4 schedule: raw s_barrier + counted vmcnt (loads span 2 iterations, never
// drained to 0 mid-loop). STAGE = 4 global_load_lds per thread -> vmcnt(4).
// EPI: 0 bf16 plain (row-major ldc)                        [weight compose]
//      4 f32  +bias+resid, transposed (out[(b*C+n)*NSP+m]) [out conv]
//      5 fused: n<512 -> Cout fp8 (v+bias)*sqscale; <1024 -> Cout2 fp8 (v+bias2)*sqscale
//               else  -> Cout3 fp8 (v+bias3), transposed (B,C,N) packed u32
template<int EPI>
__global__ __launch_bounds__(256)
void gemm_nt(const bf16* __restrict__ A, const bf16* __restrict__ B,
             const float* __restrict__ bias, const float* __restrict__ resid,
             void* __restrict__ Cout,
             int K, int lda, int ldb, int ldc, float sqscale,
             const float* __restrict__ bias2, const float* __restrict__ bias3,
             void* __restrict__ Cout2, void* __restrict__ Cout3)
{
  __shared__ char smem[2][16384];
  const int gx = gridDim.x, gy = gridDim.y;
  const int nwg = gx * gy * gridDim.z;
  const int qq = nwg >> 3;
  int hw = blockIdx.x + gx * (blockIdx.y + gy * blockIdx.z);
  int lg = (hw & 7) * qq + (hw >> 3);
  const int bx = lg % gx; lg /= gx;
  const int by = lg % gy;

  const int t  = threadIdx.x;
  const int m0 = by * 128;
  const int n0 = bx * 128;
  A += (size_t)m0 * lda;
  B += (size_t)n0 * ldb;

  const int lane = t & 63;
  const int wv = t >> 6;
  const int wr = wv >> 1, wc = wv & 1;

  f32x4 acc[4][4];
  #pragma unroll
  for (int i = 0; i < 4; ++i)
    #pragma unroll
    for (int j = 0; j < 4; ++j) acc[i][j] = (f32x4)0.0f;

  auto STAGE = [&](int buf, int kt) {
    const bf16* a = A + kt * 32;
    const bf16* b = B + kt * 32;
    #pragma unroll
    for (int i = 0; i < 2; ++i) {
      const int chunk = i * 256 + t;
      const int row = chunk >> 2, gp = chunk & 3;
      const int gg = gp ^ ((row >> 1) & 3);
      __builtin_amdgcn_global_load_lds(
          (const __attribute__((address_space(1))) unsigned int*)(a + (size_t)row * lda + gg * 8),
          (__attribute__((address_space(3))) unsigned int*)(&smem[buf][chunk * 16]),
          16, 0, 0);
    }
    #pragma unroll
    for (int i = 0; i < 2; ++i) {
      const int chunk = i * 256 + t;
      const int row = chunk >> 2, gp = chunk & 3;
      const int gg = gp ^ ((row >> 1) & 3);
      __builtin_amdgcn_global_load_lds(
          (const __attribute__((address_space(1))) unsigned int*)(b + (size_t)row * ldb + gg * 8),
          (__attribute__((address_space(3))) unsigned int*)(&smem[buf][8192 + chunk * 16]),
          16, 0, 0);
    }
  };

  const int nk = K >> 5;
  STAGE(0, 0);
  STAGE(1, 1);
  int cur = 0;
  const int r16 = lane & 15;
  const int gxo = ((lane >> 4) ^ ((r16 >> 1) & 3)) * 16;
  const int arow = wr * 64 + r16;
  const int brow = wc * 64 + r16;

  for (int kt = 0; kt < nk; ++kt) {
    if (kt + 1 < nk) asm volatile("s_waitcnt vmcnt(4)" ::: "memory");
    else             asm volatile("s_waitcnt vmcnt(0)" ::: "memory");
    __builtin_amdgcn_sched_barrier(0);
    __builtin_amdgcn_s_barrier();
    __builtin_amdgcn_sched_barrier(0);
    bf16x8 af[4], bg[4];
    #pragma unroll
    for (int i = 0; i < 4; ++i)
      af[i] = *reinterpret_cast<const bf16x8*>(&smem[cur][(arow + i * 16) * 64 + gxo]);
    #pragma unroll
    for (int j = 0; j < 4; ++j)
      bg[j] = *reinterpret_cast<const bf16x8*>(&smem[cur][8192 + (brow + j * 16) * 64 + gxo]);
    #pragma unroll
    for (int i = 0; i < 4; ++i)
      #pragma unroll
      for (int j = 0; j < 4; ++j)
        acc[i][j] = __builtin_amdgcn_mfma_f32_16x16x32_bf16(af[i], bg[j], acc[i][j], 0, 0, 0);
    __builtin_amdgcn_sched_barrier(0);
    __builtin_amdgcn_s_barrier();
    __builtin_amdgcn_sched_barrier(0);
    if (kt + 2 < nk) STAGE(cur, kt + 2);
    cur ^= 1;
  }

  // C/D map: col = lane&15, row = (lane>>4)*4 + reg.
  const int mq = (lane >> 4) * 4;
  const int nc = lane & 15;
  #pragma unroll
  for (int i = 0; i < 4; ++i) {
    #pragma unroll
    for (int j = 0; j < 4; ++j) {
      const int mm = m0 + wr * 64 + i * 16 + mq;
      const int nn = n0 + wc * 64 + j * 16 + nc;
      const f32x4 v = acc[i][j];
      if (EPI == 0) {
        bf16* o = (bf16*)Cout;
        #pragma unroll
        for (int q = 0; q < 4; ++q)
          o[(size_t)(mm + q) * ldc + nn] = __float2bfloat16(v[q]);
      } else if (EPI == 4) {
        const float bi = bias[nn];
        const int b = mm >> 12, ms = mm & (NSP - 1);
        const size_t off = ((size_t)b * C_DIM + nn) * NSP + ms;
        float* o = (float*)Cout + off;
        const float* r = resid + off;
        #pragma unroll
        for (int q = 0; q < 4; ++q) o[q] = v[q] + bi + r[q];
      } else {  // EPI == 5
        const int sec = nn >> 9;
        const int nl  = nn & 511;
        if (sec == 0) {
          const float bi = bias[nl];
          unsigned char* o = (unsigned char*)Cout;
          #pragma unroll
          for (int q = 0; q < 4; ++q)
            o[(size_t)(mm + q) * 512 + nl] = f2fp8((v[q] + bi) * sqscale);
        } else if (sec == 1) {
          const float bi = bias2[nl];
          unsigned char* o = (unsigned char*)Cout2;
          #pragma unroll
          for (int q = 0; q < 4; ++q)
            o[(size_t)(mm + q) * 512 + nl] = f2fp8((v[q] + bi) * sqscale);
        } else {
          const float bi = bias3[nl];
          const int b = mm >> 12, ms = mm & (NSP - 1);
          unsigned int pk = __builtin_amdgcn_cvt_pk_fp8_f32(v[0] + bi, v[1] + bi, 0, false);
          pk = __builtin_amdgcn_cvt_pk_fp8_f32(v[2] + bi, v[3] + bi, pk, true);
          *(unsigned int*)((unsigned char*)Cout3 + ((size_t)b * C_DIM + nl) * NSP + ms) = pk;
        }
      }
    }
  }
}

// ======================= fp8 MX NT GEMM (scores / z) =======================
// C[m,n] = sum_k A[m,k]*B[n,k], fp8 e4m3, 128x128 tile, BK=128,
// mfma_scale_f32_16x16x128_f8f6f4, unit scales. T4 schedule, vmcnt(8).
// EPI 0: P = exp(v) fp8 -> Cout(+bz*sC), row partials -> aux[(bz*4096+row)*64+bx*2+wc]
// EPI 1: bf16 v * aux[bz*4096+row] -> ((bz*4096+row)*512 + nn)
template<int EPI>
__global__ __launch_bounds__(256)
void gemm_f8(const unsigned char* __restrict__ A, const unsigned char* __restrict__ B,
             void* __restrict__ Cout, int K, int lda, int ldb, int ldc,
             long sA, long sB, long sC, float* __restrict__ aux)
{
  __shared__ char smem[2][32768];
  const int gx = gridDim.x, gy = gridDim.y;
  const int nwg = gx * gy * gridDim.z;
  const int qq = nwg >> 3;
  int hw = blockIdx.x + gx * (blockIdx.y + gy * blockIdx.z);
  int lg = (hw & 7) * qq + (hw >> 3);
  const int bx = lg % gx; lg /= gx;
  const int by = lg % gy;
  const int bz = lg / gy;

  const int t  = threadIdx.x;
  const int m0 = by * 128;
  const int n0 = bx * 128;
  A += (size_t)bz * sA + (size_t)m0 * lda;
  B += (size_t)bz * sB + (size_t)n0 * ldb;

  const int lane = t & 63;
  const int wv = t >> 6;
  const int wr = wv >> 1, wc = wv & 1;
  const int r16 = lane & 15, g4 = lane >> 4;

  f32x4 acc[4][4];
  #pragma unroll
  for (int i = 0; i < 4; ++i)
    #pragma unroll
    for (int j = 0; j < 4; ++j) acc[i][j] = (f32x4)0.0f;

  auto STAGE = [&](int buf, int kt) {
    const unsigned char* a = A + kt * 128;
    const unsigned char* b = B + kt * 128;
    #pragma unroll
    for (int i = 0; i < 4; ++i) {
      const int chunk = i * 256 + t;
      const int row = chunk >> 3, gp = chunk & 7;
      const int gg = gp ^ (row & 7);
      __builtin_amdgcn_global_load_lds(
          (const __attribute__((address_space(1))) unsigned int*)(a + (size_t)row * lda + gg * 16),
          (__attribute__((address_space(3))) unsigned int*)(&smem[buf][chunk * 16]),
          16, 0, 0);
    }
    #pragma unroll
    for (int i = 0; i < 4; ++i) {
      const int chunk = i * 256 + t;
      const int row = chunk >> 3, gp = chunk & 7;
      const int gg = gp ^ (row & 7);
      __builtin_amdgcn_global_load_lds(
          (const __attribute__((address_space(1))) unsigned int*)(b + (size_t)row * ldb + gg * 16),
          (__attribute__((address_space(3))) unsigned int*)(&smem[buf][16384 + chunk * 16]),
          16, 0, 0);
    }
  };

  const int nk = K >> 7;
  STAGE(0, 0);
  STAGE(1, 1);
  int cur = 0;
  const int p0 = g4 * 2;

  for (int kt = 0; kt < nk; ++kt) {
    if (kt + 1 < nk) asm volatile("s_waitcnt vmcnt(8)" ::: "memory");
    else             asm volatile("s_waitcnt vmcnt(0)" ::: "memory");
    __builtin_amdgcn_sched_barrier(0);
    __builtin_amdgcn_s_barrier();
    __builtin_amdgcn_sched_barrier(0);
    i32x8 af[4], bg[4];
    #pragma unroll
    for (int i = 0; i < 4; ++i) {
      const int row = wr * 64 + i * 16 + r16;
      const i32x4 lo = *(const i32x4*)(&smem[cur][row * 128 + ((p0    ) ^ (row & 7)) * 16]);
      const i32x4 hi = *(const i32x4*)(&smem[cur][row * 128 + ((p0 + 1) ^ (row & 7)) * 16]);
      #pragma unroll
      for (int q = 0; q < 4; ++q) { af[i][q] = lo[q]; af[i][4 + q] = hi[q]; }
    }
    #pragma unroll
    for (int j = 0; j < 4; ++j) {
      const int row = wc * 64 + j * 16 + r16;
      const i32x4 lo = *(const i32x4*)(&smem[cur][16384 + row * 128 + ((p0    ) ^ (row & 7)) * 16]);
      const i32x4 hi = *(const i32x4*)(&smem[cur][16384 + row * 128 + ((p0 + 1) ^ (row & 7)) * 16]);
      #pragma unroll
      for (int q = 0; q < 4; ++q) { bg[j][q] = lo[q]; bg[j][4 + q] = hi[q]; }
    }
    #pragma unroll
    for (int i = 0; i < 4; ++i)
      #pragma unroll
      for (int j = 0; j < 4; ++j)
        acc[i][j] = __builtin_amdgcn_mfma_scale_f32_16x16x128_f8f6f4(
            af[i], bg[j], acc[i][j], 0, 0, 0, 0x7F7F7F7Fu, 0, 0x7F7F7F7Fu);
    __builtin_amdgcn_sched_barrier(0);
    __builtin_amdgcn_s_barrier();
    __builtin_amdgcn_sched_barrier(0);
    if (kt + 2 < nk) STAGE(cur, kt + 2);
    cur ^= 1;
  }

  const int mq = g4 * 4;
  #pragma unroll
  for (int i = 0; i < 4; ++i) {
    float rs[4] = {0.0f, 0.0f, 0.0f, 0.0f};
    #pragma unroll
    for (int j = 0; j < 4; ++j) {
      const int mm = m0 + wr * 64 + i * 16 + mq;
      const int nn = n0 + wc * 64 + j * 16 + r16;
      const f32x4 v = acc[i][j];
      if (EPI == 0) {
        unsigned char* o = (unsigned char*)Cout + (size_t)bz * sC;
        #pragma unroll
        for (int q = 0; q < 4; ++q) {
          const float e = __expf(v[q]);
          o[(size_t)(mm + q) * ldc + nn] = f2fp8(e);
          rs[q] += e;
        }
      } else {
        bf16* o = (bf16*)Cout;
        #pragma unroll
        for (int q = 0; q < 4; ++q) {
          const float li = aux[(size_t)bz * NSP + mm + q];
          o[((size_t)bz * NSP + mm + q) * 512 + nn] = __float2bfloat16(v[q] * li);
        }
      }
    }
    if (EPI == 0) {
      #pragma unroll
      for (int msk = 1; msk < 16; msk <<= 1)
        #pragma unroll
        for (int q = 0; q < 4; ++q) rs[q] += __shfl_xor(rs[q], msk);
      if (r16 == 0) {
        const int mm = m0 + wr * 64 + i * 16 + mq;
        #pragma unroll
        for (int q = 0; q < 4; ++q)
          aux[((size_t)bz * NSP + mm + q) * 64 + bx * 2 + wc] = rs[q];
      }
    }
  }
}

extern "C" void kernel_launch(void* const* d_in, const int* in_sizes, int n_in,
                              void* d_out, int out_size, void* d_ws, size_t ws_size,
                              hipStream_t stream)
{
  const float* x     = (const float*)d_in[0];
  const float* w_th  = (const float*)d_in[1];
  const float* b_th  = (const float*)d_in[2];
  const float* w_ph  = (const float*)d_in[3];
  const float* b_ph  = (const float*)d_in[4];
  const float* w_g   = (const float*)d_in[5];
  const float* b_g   = (const float*)d_in[6];
  const float* w_out = (const float*)d_in[7];
  const float* b_out = (const float*)d_in[8];

  const size_t NC = (size_t)16384 * C_DIM;
  char* p = (char*)d_ws;
  auto take = [&](size_t bytes) {
    char* r = p; p += (bytes + 255) & ~(size_t)255; return r;
  };
  bf16* XT  = (bf16*)take(NC * 2);
  bf16* ZT  = (bf16*)take(NC * 2);
  unsigned char* TH8 = (unsigned char*)take(NC);        // (B*N, C) fp8, pre-scaled
  unsigned char* PH8 = (unsigned char*)take(NC);        // (B*N, C) fp8, pre-scaled
  unsigned char* G8  = (unsigned char*)take(NC);        // (B, C, N) fp8
  unsigned char* P8  = (unsigned char*)take((size_t)4 * NSP * NSP);  // 64 MB
  bf16* WCAT  = (bf16*)take((size_t)1536 * 512 * 2);    // [th|ph|g] original
  bf16* WGT   = (bf16*)take((size_t)512 * 512 * 2);     // Wg transposed
  bf16* WCATC = (bf16*)take((size_t)1536 * 512 * 2);    // composed W' = W @ Wg
  bf16* WOUT  = (bf16*)take((size_t)512 * 512 * 2);
  float* Bc   = (float*)take((size_t)1536 * 4);         // composed biases
  float* Lp   = (float*)take((size_t)4 * NSP * 64 * 4);
  float* Li   = (float*)take((size_t)4 * NSP * 4);

  const dim3 blk(256);
  const float sqscale = 0.21022410381342864f;  // 512^-0.25
  const long sact = (long)NSP * C_DIM;
  const long sS   = (long)NSP * NSP;

  cvt_bf16<<<dim3(256), blk, 0, stream>>>(w_th,  WCAT);
  cvt_bf16<<<dim3(256), blk, 0, stream>>>(w_ph,  WCAT + (size_t)512 * 512);
  cvt_bf16<<<dim3(256), blk, 0, stream>>>(w_g,   WCAT + (size_t)1024 * 512);
  cvt_bf16<<<dim3(256), blk, 0, stream>>>(w_out, WOUT);
  cvt_bf16_T<<<dim3(16, 16), blk, 0, stream>>>(w_g, WGT);
  bias_compose<<<dim3(6), blk, 0, stream>>>(w_th, b_th, w_ph, b_ph, w_g, b_g, Bc);

  // W' = [Wth;Wph;Wg] @ Wg   (NT with B = Wg^T), M=1536 N=512 K=512
  gemm_nt<0><<<dim3(4, 12), blk, 0, stream>>>(WCAT, WGT, nullptr, nullptr, WCATC,
      512, 512, 512, 512, 1.0f, nullptr, nullptr, nullptr, nullptr);

  transpose_x<<<dim3(NSP / 32, C_DIM / 32, 4), blk, 0, stream>>>(x, XT);

  // theta/phi (fp8, *512^-1/4) and g (fp8, (B,C,N)) DIRECTLY from x via composed weights
  gemm_nt<5><<<dim3(12, 128), blk, 0, stream>>>(XT, WCATC, Bc, nullptr, TH8,
      512, 512, 512, 512, sqscale, Bc + 512, Bc + 1024, PH8, G8);

  // P = exp(theta^T phi) fp8 + row partials
  gemm_f8<0><<<dim3(32, 32, 4), blk, 0, stream>>>(TH8, PH8, P8,
      512, 512, 512, NSP, sact, sact, sS, Lp);
  lreduce<<<dim3(64), blk, 0, stream>>>(Lp, Li);
  // Z[n, c] = (sum_m P[n,m] G8[c,m]) / l[n]  -> ZT bf16 (B*N, C)
  gemm_f8<1><<<dim3(4, 32, 4), blk, 0, stream>>>(P8, G8, ZT,
      4096, 4096, 4096, 512, sS, sact, 0, Li);

  // out = x + out-conv(z)
  gemm_nt<4><<<dim3(4, 128), blk, 0, stream>>>(ZT, WOUT, b_out, x, d_out,
      512, 512, 512, 512, 1.0f, nullptr, nullptr, nullptr, nullptr);
}

// Round 9
// 275.665 us; speedup vs baseline: 1.0643x; 1.0643x over previous
//
#include <hip/hip_runtime.h>
#include <hip/hip_bf16.h>

typedef __hip_bfloat16 bf16;
typedef __attribute__((ext_vector_type(8))) short          bf16x8;
typedef __attribute__((ext_vector_type(4))) float          f32x4;
typedef __attribute__((ext_vector_type(4))) int            i32x4;
typedef __attribute__((ext_vector_type(8))) int            i32x8;

#define C_DIM 512
#define NSP   4096

__device__ __forceinline__ unsigned char f2fp8(float x) {
  return (unsigned char)(__builtin_amdgcn_cvt_pk_fp8_f32(x, x, 0, false) & 0xFF);
}

// ---------------- merged weight prep: cvt [th|ph|g|out] + transpose(w_g) ----------------
// blocks 0..1023: f32->bf16 cvt (4 elems/thread). blocks 1024..1279: w_g^T tiles.
__global__ __launch_bounds__(256)
void prep_weights(const float* __restrict__ w_th, const float* __restrict__ w_ph,
                  const float* __restrict__ w_g,  const float* __restrict__ w_out,
                  bf16* __restrict__ WCAT, bf16* __restrict__ WOUT,
                  bf16* __restrict__ WGT)
{
  const int blk = blockIdx.x;
  if (blk < 1024) {
    const int sec = blk >> 8;                 // 0:th 1:ph 2:g 3:out
    const int i = ((blk & 255) * 256 + threadIdx.x) * 4;
    const float* s = (sec == 0) ? w_th : (sec == 1) ? w_ph : (sec == 2) ? w_g : w_out;
    bf16* d = (sec == 3) ? WOUT : (WCAT + (size_t)sec * 512 * 512);
    const float4 v = *reinterpret_cast<const float4*>(s + i);
    d[i + 0] = __float2bfloat16(v.x);
    d[i + 1] = __float2bfloat16(v.y);
    d[i + 2] = __float2bfloat16(v.z);
    d[i + 3] = __float2bfloat16(v.w);
  } else {
    __shared__ float tile[32][33];
    const int tb = blk - 1024;                // 0..255
    const int c0 = (tb & 15) * 32, r0 = (tb >> 4) * 32;
    const int tx = threadIdx.x & 31, ty = threadIdx.x >> 5;
    #pragma unroll
    for (int i = 0; i < 32; i += 8)
      tile[ty + i][tx] = w_g[(size_t)(r0 + ty + i) * 512 + c0 + tx];
    __syncthreads();
    #pragma unroll
    for (int i = 0; i < 32; i += 8)
      WGT[(size_t)(c0 + ty + i) * 512 + r0 + tx] = __float2bfloat16(tile[tx][ty + i]);
  }
}

// ---------------- composed biases, one wave per output row (24 blocks) ----------------
__global__ __launch_bounds__(256)
void bias_compose(const float* __restrict__ w_th, const float* __restrict__ b_th,
                  const float* __restrict__ w_ph, const float* __restrict__ b_ph,
                  const float* __restrict__ w_g,  const float* __restrict__ b_g,
                  float* __restrict__ out)
{
  const int wid = (blockIdx.x * 256 + threadIdx.x) >> 6;   // 0..1535
  const int lane = threadIdx.x & 63;
  const int w = wid / 512, o = wid & 511;
  const float* W  = (w == 0) ? w_th : (w == 1) ? w_ph : w_g;
  const float* bb = (w == 0) ? b_th : (w == 1) ? b_ph : b_g;
  const float4* row = reinterpret_cast<const float4*>(W + (size_t)o * 512);
  const float4* bg4 = reinterpret_cast<const float4*>(b_g);
  float s = 0.0f;
  #pragma unroll
  for (int i = 0; i < 2; ++i) {
    const float4 a = row[lane * 2 + i], c = bg4[lane * 2 + i];
    s += a.x * c.x + a.y * c.y + a.z * c.z + a.w * c.w;
  }
  #pragma unroll
  for (int msk = 1; msk < 64; msk <<= 1) s += __shfl_xor(s, msk);
  if (lane == 0) out[wid] = s + bb[o];
}

// ---------------- x (B,C,N) f32 -> XT (B*N, C) bf16 ----------------
__global__ __launch_bounds__(256) void transpose_x(const float* __restrict__ x,
                                                   bf16* __restrict__ xt) {
  __shared__ float tile[32][33];
  const int n0 = blockIdx.x * 32, c0 = blockIdx.y * 32, b = blockIdx.z;
  const int tx = threadIdx.x & 31, ty = threadIdx.x >> 5;
  const float* src = x + ((size_t)b * C_DIM + c0) * NSP + n0;
  #pragma unroll
  for (int i = 0; i < 32; i += 8)
    tile[ty + i][tx] = src[(size_t)(ty + i) * NSP + tx];
  __syncthreads();
  bf16* dst = xt + ((size_t)b * NSP + n0) * C_DIM + c0;
  #pragma unroll
  for (int i = 0; i < 32; i += 8)
    dst[(size_t)(ty + i) * C_DIM + tx] = __float2bfloat16(tile[tx][ty + i]);
}

// ---------------- Linv: Lp[16384][64] partial sums -> 1/rowsum ----------------
__global__ __launch_bounds__(256) void lreduce(const float* __restrict__ Lp,
                                               float* __restrict__ Linv) {
  const int r = blockIdx.x * 256 + threadIdx.x;
  const float4* p = reinterpret_cast<const float4*>(Lp + (size_t)r * 64);
  float s = 0.0f;
  #pragma unroll
  for (int i = 0; i < 16; ++i) { const float4 v = p[i]; s += (v.x + v.y) + (v.z + v.w); }
  Linv[r] = 1.0f / s;
}

// ======================= bf16 NT GEMM =======================
// 128x128 tile, BK=32, 256 thr, 16x16x32 bf16 MFMA.
// T4 counted-vmcnt schedule, manual unroll-2 (buf compile-time), hoisted offsets.
// EPI: 0 bf16 plain; 4 f32 +bias+resid transposed; 5 fused th/ph/g fp8 triple-out.
template<int EPI>
__global__ __launch_bounds__(256)
void gemm_nt(const bf16* __restrict__ A, const bf16* __restrict__ B,
             const float* __restrict__ bias, const float* __restrict__ resid,
             void* __restrict__ Cout,
             int K, int lda, int ldb, int ldc, float sqscale,
             const float* __restrict__ bias2, const float* __restrict__ bias3,
             void* __restrict__ Cout2, void* __restrict__ Cout3)
{
  __shared__ char smem[2][16384];
  const int gx = gridDim.x, gy = gridDim.y;
  const int nwg = gx * gy * gridDim.z;
  const int qq = nwg >> 3;
  int hw = blockIdx.x + gx * (blockIdx.y + gy * blockIdx.z);
  int lg = (hw & 7) * qq + (hw >> 3);
  const int bx = lg % gx; lg /= gx;
  const int by = lg % gy;

  const int t  = threadIdx.x;
  const int m0 = by * 128;
  const int n0 = bx * 128;
  A += (size_t)m0 * lda;
  B += (size_t)n0 * ldb;

  const int lane = t & 63;
  const int wv = t >> 6;
  const int wr = wv >> 1, wc = wv & 1;

  f32x4 acc[4][4];
  #pragma unroll
  for (int i = 0; i < 4; ++i)
    #pragma unroll
    for (int j = 0; j < 4; ++j) acc[i][j] = (f32x4)0.0f;

  // staging addressing (per-thread, loop-invariant parts hoisted by compiler)
  const int s_row = t >> 2, s_gp = t & 3;
  const int s_gg = s_gp ^ ((s_row >> 1) & 3);
  const int s_row2 = (256 + t) >> 2, s_gp2 = t & 3;
  const int s_gg2 = s_gp2 ^ ((s_row2 >> 1) & 3);

  auto STAGE = [&](int buf, int kt) {
    const bf16* a = A + kt * 32;
    const bf16* b = B + kt * 32;
    __builtin_amdgcn_global_load_lds(
        (const __attribute__((address_space(1))) unsigned int*)(a + (size_t)s_row * lda + s_gg * 8),
        (__attribute__((address_space(3))) unsigned int*)(&smem[buf][t * 16]), 16, 0, 0);
    __builtin_amdgcn_global_load_lds(
        (const __attribute__((address_space(1))) unsigned int*)(a + (size_t)s_row2 * lda + s_gg2 * 8),
        (__attribute__((address_space(3))) unsigned int*)(&smem[buf][(256 + t) * 16]), 16, 0, 0);
    __builtin_amdgcn_global_load_lds(
        (const __attribute__((address_space(1))) unsigned int*)(b + (size_t)s_row * ldb + s_gg * 8),
        (__attribute__((address_space(3))) unsigned int*)(&smem[buf][8192 + t * 16]), 16, 0, 0);
    __builtin_amdgcn_global_load_lds(
        (const __attribute__((address_space(1))) unsigned int*)(b + (size_t)s_row2 * ldb + s_gg2 * 8),
        (__attribute__((address_space(3))) unsigned int*)(&smem[buf][8192 + (256 + t) * 16]), 16, 0, 0);
  };

  const int nk = K >> 5;
  STAGE(0, 0);
  STAGE(1, 1);
  const int r16 = lane & 15;
  const int gxo = ((lane >> 4) ^ ((r16 >> 1) & 3)) * 16;

  int offA[4], offB[4];
  #pragma unroll
  for (int i = 0; i < 4; ++i) offA[i] = (wr * 64 + r16 + i * 16) * 64 + gxo;
  #pragma unroll
  for (int j = 0; j < 4; ++j) offB[j] = 8192 + (wc * 64 + r16 + j * 16) * 64 + gxo;

  auto ITER = [&](int buf, int kt) {
    if (kt + 1 < nk) asm volatile("s_waitcnt vmcnt(4)" ::: "memory");
    else             asm volatile("s_waitcnt vmcnt(0)" ::: "memory");
    __builtin_amdgcn_sched_barrier(0);
    __builtin_amdgcn_s_barrier();
    __builtin_amdgcn_sched_barrier(0);
    bf16x8 af[4], bg[4];
    #pragma unroll
    for (int i = 0; i < 4; ++i)
      af[i] = *reinterpret_cast<const bf16x8*>(&smem[buf][offA[i]]);
    #pragma unroll
    for (int j = 0; j < 4; ++j)
      bg[j] = *reinterpret_cast<const bf16x8*>(&smem[buf][offB[j]]);
    #pragma unroll
    for (int i = 0; i < 4; ++i)
      #pragma unroll
      for (int j = 0; j < 4; ++j)
        acc[i][j] = __builtin_amdgcn_mfma_f32_16x16x32_bf16(af[i], bg[j], acc[i][j], 0, 0, 0);
    __builtin_amdgcn_sched_barrier(0);
    __builtin_amdgcn_s_barrier();
    __builtin_amdgcn_sched_barrier(0);
    if (kt + 2 < nk) STAGE(buf, kt + 2);
  };

  for (int kt = 0; kt < nk; kt += 2) {
    ITER(0, kt);
    ITER(1, kt + 1);
  }

  // C/D map: col = lane&15, row = (lane>>4)*4 + reg.
  const int mq = (lane >> 4) * 4;
  const int nc = lane & 15;
  #pragma unroll
  for (int i = 0; i < 4; ++i) {
    #pragma unroll
    for (int j = 0; j < 4; ++j) {
      const int mm = m0 + wr * 64 + i * 16 + mq;
      const int nn = n0 + wc * 64 + j * 16 + nc;
      const f32x4 v = acc[i][j];
      if (EPI == 0) {
        bf16* o = (bf16*)Cout;
        #pragma unroll
        for (int q = 0; q < 4; ++q)
          o[(size_t)(mm + q) * ldc + nn] = __float2bfloat16(v[q]);
      } else if (EPI == 4) {
        const float bi = bias[nn];
        const int b = mm >> 12, ms = mm & (NSP - 1);
        const size_t off = ((size_t)b * C_DIM + nn) * NSP + ms;
        float* o = (float*)Cout + off;
        const float* r = resid + off;
        #pragma unroll
        for (int q = 0; q < 4; ++q) o[q] = v[q] + bi + r[q];
      } else {  // EPI == 5
        const int sec = nn >> 9;
        const int nl  = nn & 511;
        if (sec == 0) {
          const float bi = bias[nl];
          unsigned char* o = (unsigned char*)Cout;
          #pragma unroll
          for (int q = 0; q < 4; ++q)
            o[(size_t)(mm + q) * 512 + nl] = f2fp8((v[q] + bi) * sqscale);
        } else if (sec == 1) {
          const float bi = bias2[nl];
          unsigned char* o = (unsigned char*)Cout2;
          #pragma unroll
          for (int q = 0; q < 4; ++q)
            o[(size_t)(mm + q) * 512 + nl] = f2fp8((v[q] + bi) * sqscale);
        } else {
          const float bi = bias3[nl];
          const int b = mm >> 12, ms = mm & (NSP - 1);
          unsigned int pk = __builtin_amdgcn_cvt_pk_fp8_f32(v[0] + bi, v[1] + bi, 0, false);
          pk = __builtin_amdgcn_cvt_pk_fp8_f32(v[2] + bi, v[3] + bi, pk, true);
          *(unsigned int*)((unsigned char*)Cout3 + ((size_t)b * C_DIM + nl) * NSP + ms) = pk;
        }
      }
    }
  }
}

// ======================= fp8 MX NT GEMM (scores / z) =======================
// 128x128 tile, BK=128, mfma_scale_f32_16x16x128_f8f6f4, unit scales.
// T4 counted-vmcnt, unroll-2, hoisted offsets, shufflevector fragment concat.
// EPI 0: P = exp(v) fp8 + row partials; EPI 1: bf16 v * Linv[row].
template<int EPI>
__global__ __launch_bounds__(256)
void gemm_f8(const unsigned char* __restrict__ A, const unsigned char* __restrict__ B,
             void* __restrict__ Cout, int K, int lda, int ldb, int ldc,
             long sA, long sB, long sC, float* __restrict__ aux)
{
  __shared__ char smem[2][32768];
  const int gx = gridDim.x, gy = gridDim.y;
  const int nwg = gx * gy * gridDim.z;
  const int qq = nwg >> 3;
  int hw = blockIdx.x + gx * (blockIdx.y + gy * blockIdx.z);
  int lg = (hw & 7) * qq + (hw >> 3);
  const int bx = lg % gx; lg /= gx;
  const int by = lg % gy;
  const int bz = lg / gy;

  const int t  = threadIdx.x;
  const int m0 = by * 128;
  const int n0 = bx * 128;
  A += (size_t)bz * sA + (size_t)m0 * lda;
  B += (size_t)bz * sB + (size_t)n0 * ldb;

  const int lane = t & 63;
  const int wv = t >> 6;
  const int wr = wv >> 1, wc = wv & 1;
  const int r16 = lane & 15, g4 = lane >> 4;

  f32x4 acc[4][4];
  #pragma unroll
  for (int i = 0; i < 4; ++i)
    #pragma unroll
    for (int j = 0; j < 4; ++j) acc[i][j] = (f32x4)0.0f;

  auto STAGE = [&](int buf, int kt) {
    const unsigned char* a = A + kt * 128;
    const unsigned char* b = B + kt * 128;
    #pragma unroll
    for (int i = 0; i < 4; ++i) {
      const int chunk = i * 256 + t;
      const int row = chunk >> 3, gp = chunk & 7;
      const int gg = gp ^ (row & 7);
      __builtin_amdgcn_global_load_lds(
          (const __attribute__((address_space(1))) unsigned int*)(a + (size_t)row * lda + gg * 16),
          (__attribute__((address_space(3))) unsigned int*)(&smem[buf][chunk * 16]), 16, 0, 0);
    }
    #pragma unroll
    for (int i = 0; i < 4; ++i) {
      const int chunk = i * 256 + t;
      const int row = chunk >> 3, gp = chunk & 7;
      const int gg = gp ^ (row & 7);
      __builtin_amdgcn_global_load_lds(
          (const __attribute__((address_space(1))) unsigned int*)(b + (size_t)row * ldb + gg * 16),
          (__attribute__((address_space(3))) unsigned int*)(&smem[buf][16384 + chunk * 16]), 16, 0, 0);
    }
  };

  const int nk = K >> 7;
  STAGE(0, 0);
  STAGE(1, 1);
  const int p0 = g4 * 2;

  // hoisted LDS byte offsets (lo/hi granule per fragment)
  int oAl[4], oAh[4], oBl[4], oBh[4];
  #pragma unroll
  for (int i = 0; i < 4; ++i) {
    const int row = wr * 64 + i * 16 + r16;
    oAl[i] = row * 128 + ((p0    ) ^ (row & 7)) * 16;
    oAh[i] = row * 128 + ((p0 + 1) ^ (row & 7)) * 16;
  }
  #pragma unroll
  for (int j = 0; j < 4; ++j) {
    const int row = wc * 64 + j * 16 + r16;
    oBl[j] = 16384 + row * 128 + ((p0    ) ^ (row & 7)) * 16;
    oBh[j] = 16384 + row * 128 + ((p0 + 1) ^ (row & 7)) * 16;
  }

  auto ITER = [&](int buf, int kt) {
    if (kt + 1 < nk) asm volatile("s_waitcnt vmcnt(8)" ::: "memory");
    else             asm volatile("s_waitcnt vmcnt(0)" ::: "memory");
    __builtin_amdgcn_sched_barrier(0);
    __builtin_amdgcn_s_barrier();
    __builtin_amdgcn_sched_barrier(0);
    i32x8 af[4], bg[4];
    #pragma unroll
    for (int i = 0; i < 4; ++i) {
      const i32x4 lo = *(const i32x4*)(&smem[buf][oAl[i]]);
      const i32x4 hi = *(const i32x4*)(&smem[buf][oAh[i]]);
      af[i] = __builtin_shufflevector(lo, hi, 0, 1, 2, 3, 4, 5, 6, 7);
    }
    #pragma unroll
    for (int j = 0; j < 4; ++j) {
      const i32x4 lo = *(const i32x4*)(&smem[buf][oBl[j]]);
      const i32x4 hi = *(const i32x4*)(&smem[buf][oBh[j]]);
      bg[j] = __builtin_shufflevector(lo, hi, 0, 1, 2, 3, 4, 5, 6, 7);
    }
    #pragma unroll
    for (int i = 0; i < 4; ++i)
      #pragma unroll
      for (int j = 0; j < 4; ++j)
        acc[i][j] = __builtin_amdgcn_mfma_scale_f32_16x16x128_f8f6f4(
            af[i], bg[j], acc[i][j], 0, 0, 0, 0x7F7F7F7Fu, 0, 0x7F7F7F7Fu);
    __builtin_amdgcn_sched_barrier(0);
    __builtin_amdgcn_s_barrier();
    __builtin_amdgcn_sched_barrier(0);
    if (kt + 2 < nk) STAGE(buf, kt + 2);
  };

  for (int kt = 0; kt < nk; kt += 2) {
    ITER(0, kt);
    ITER(1, kt + 1);
  }

  const int mq = g4 * 4;
  #pragma unroll
  for (int i = 0; i < 4; ++i) {
    float rs[4] = {0.0f, 0.0f, 0.0f, 0.0f};
    #pragma unroll
    for (int j = 0; j < 4; ++j) {
      const int mm = m0 + wr * 64 + i * 16 + mq;
      const int nn = n0 + wc * 64 + j * 16 + r16;
      const f32x4 v = acc[i][j];
      if (EPI == 0) {
        unsigned char* o = (unsigned char*)Cout + (size_t)bz * sC;
        #pragma unroll
        for (int q = 0; q < 4; ++q) {
          const float e = __expf(v[q]);
          o[(size_t)(mm + q) * ldc + nn] = f2fp8(e);
          rs[q] += e;
        }
      } else {
        bf16* o = (bf16*)Cout;
        #pragma unroll
        for (int q = 0; q < 4; ++q) {
          const float li = aux[(size_t)bz * NSP + mm + q];
          o[((size_t)bz * NSP + mm + q) * 512 + nn] = __float2bfloat16(v[q] * li);
        }
      }
    }
    if (EPI == 0) {
      #pragma unroll
      for (int msk = 1; msk < 16; msk <<= 1)
        #pragma unroll
        for (int q = 0; q < 4; ++q) rs[q] += __shfl_xor(rs[q], msk);
      if (r16 == 0) {
        const int mm = m0 + wr * 64 + i * 16 + mq;
        #pragma unroll
        for (int q = 0; q < 4; ++q)
          aux[((size_t)bz * NSP + mm + q) * 64 + bx * 2 + wc] = rs[q];
      }
    }
  }
}

extern "C" void kernel_launch(void* const* d_in, const int* in_sizes, int n_in,
                              void* d_out, int out_size, void* d_ws, size_t ws_size,
                              hipStream_t stream)
{
  const float* x     = (const float*)d_in[0];
  const float* w_th  = (const float*)d_in[1];
  const float* b_th  = (const float*)d_in[2];
  const float* w_ph  = (const float*)d_in[3];
  const float* b_ph  = (const float*)d_in[4];
  const float* w_g   = (const float*)d_in[5];
  const float* b_g   = (const float*)d_in[6];
  const float* w_out = (const float*)d_in[7];
  const float* b_out = (const float*)d_in[8];

  const size_t NC = (size_t)16384 * C_DIM;
  char* p = (char*)d_ws;
  auto take = [&](size_t bytes) {
    char* r = p; p += (bytes + 255) & ~(size_t)255; return r;
  };
  bf16* XT  = (bf16*)take(NC * 2);
  bf16* ZT  = (bf16*)take(NC * 2);
  unsigned char* TH8 = (unsigned char*)take(NC);
  unsigned char* PH8 = (unsigned char*)take(NC);
  unsigned char* G8  = (unsigned char*)take(NC);
  unsigned char* P8  = (unsigned char*)take((size_t)4 * NSP * NSP);  // 64 MB
  bf16* WCAT  = (bf16*)take((size_t)1536 * 512 * 2);
  bf16* WGT   = (bf16*)take((size_t)512 * 512 * 2);
  bf16* WCATC = (bf16*)take((size_t)1536 * 512 * 2);
  bf16* WOUT  = (bf16*)take((size_t)512 * 512 * 2);
  float* Bc   = (float*)take((size_t)1536 * 4);
  float* Lp   = (float*)take((size_t)4 * NSP * 64 * 4);
  float* Li   = (float*)take((size_t)4 * NSP * 4);

  const dim3 blk(256);
  const float sqscale = 0.21022410381342864f;  // 512^-0.25
  const long sact = (long)NSP * C_DIM;
  const long sS   = (long)NSP * NSP;

  prep_weights<<<dim3(1280), blk, 0, stream>>>(w_th, w_ph, w_g, w_out, WCAT, WOUT, WGT);
  bias_compose<<<dim3(24), blk, 0, stream>>>(w_th, b_th, w_ph, b_ph, w_g, b_g, Bc);

  // W' = [Wth;Wph;Wg] @ Wg   (NT with B = Wg^T), M=1536 N=512 K=512
  gemm_nt<0><<<dim3(4, 12), blk, 0, stream>>>(WCAT, WGT, nullptr, nullptr, WCATC,
      512, 512, 512, 512, 1.0f, nullptr, nullptr, nullptr, nullptr);

  transpose_x<<<dim3(NSP / 32, C_DIM / 32, 4), blk, 0, stream>>>(x, XT);

  // theta/phi (fp8, *512^-1/4) and g (fp8, (B,C,N)) from x via composed weights
  gemm_nt<5><<<dim3(12, 128), blk, 0, stream>>>(XT, WCATC, Bc, nullptr, TH8,
      512, 512, 512, 512, sqscale, Bc + 512, Bc + 1024, PH8, G8);

  // P = exp(theta^T phi) fp8 + row partials
  gemm_f8<0><<<dim3(32, 32, 4), blk, 0, stream>>>(TH8, PH8, P8,
      512, 512, 512, NSP, sact, sact, sS, Lp);
  lreduce<<<dim3(64), blk, 0, stream>>>(Lp, Li);
  // Z[n, c] = (sum_m P[n,m] G8[c,m]) / l[n]  -> ZT bf16 (B*N, C)
  gemm_f8<1><<<dim3(4, 32, 4), blk, 0, stream>>>(P8, G8, ZT,
      4096, 4096, 4096, 512, sS, sact, 0, Li);

  // out = x + out-conv(z)
  gemm_nt<4><<<dim3(4, 128), blk, 0, stream>>>(ZT, WOUT, b_out, x, d_out,
      512, 512, 512, 512, 1.0f, nullptr, nullptr, nullptr, nullptr);
}